// Round 2
// baseline (138.185 us; speedup 1.0000x reference)
//
#include <hip/hip_runtime.h>
#include <hip/hip_bf16.h>

typedef __attribute__((ext_vector_type(8))) short short8;
typedef __attribute__((ext_vector_type(8))) float f32x8;
typedef __attribute__((ext_vector_type(4))) float f32x4;
typedef unsigned short u16;

#define BQ 8
#define LL 2048
#define NN 1024
#define HH 64
#define BL (BQ * LL) /* 16384 */

static __device__ __forceinline__ u16 f2bf(float f) {
  union { float f; unsigned int u; } cv;
  cv.f = f;
  unsigned int u = cv.u;
  unsigned int rounded = u + 0x7FFFu + ((u >> 16) & 1u);  // RNE
  return (u16)(rounded >> 16);
}

// ---------------------------------------------------------------------------
// Kernel 0: pack W^T[m][h][k] = bf16(W[m][k][h])  (m: 0=q,1=k,2=v). W is f32.
// ---------------------------------------------------------------------------
__global__ __launch_bounds__(256) void wt_pack(const float* __restrict__ Wq,
                                               const float* __restrict__ Wk,
                                               const float* __restrict__ Wv,
                                               u16* __restrict__ wt) {
  int gid = blockIdx.x * 256 + threadIdx.x;   // [0, 3*65536)
  int m = gid >> 16;
  int rem = gid & 65535;
  int h = rem >> 10;
  int k = rem & 1023;
  const float* src = (m == 0) ? Wq : (m == 1) ? Wk : Wv;
  wt[gid] = f2bf(src[k * HH + h]);
}

// ---------------------------------------------------------------------------
// Kernel 1: q/k/v = x @ W{q,k,v}; q additionally scaled by N^-0.5 = 1/32.
// x is f32 (converted to bf16 in-register). 64 rows/block, 4 waves x 16 rows.
// ---------------------------------------------------------------------------
__global__ __launch_bounds__(256) void qkv_proj(const float* __restrict__ x,
                                                const u16* __restrict__ wt,
                                                u16* __restrict__ qs,
                                                u16* __restrict__ ks,
                                                u16* __restrict__ vs) {
  __shared__ u16 wts[3 * 64 * 40];
  const int tid = threadIdx.x;
  const int lane = tid & 63;
  const int wv = tid >> 6;
  const int r = lane & 15;
  const int g = lane >> 4;
  const int row0 = blockIdx.x * 64 + wv * 16;

  f32x4 acc[3][4] = {};
  const float* xptr = x + (row0 + r) * NN + 8 * g;

  for (int k0 = 0; k0 < NN; k0 += 32) {
    // stage 3*64*32 bf16 of W^T, padded stride 40
#pragma unroll
    for (int cc = 0; cc < 3; ++cc) {
      int c = tid + (cc << 8);
      int m = c >> 8;
      int rem = c & 255;
      int h = rem >> 2;
      int kb = rem & 3;
      short8 val = *(const short8*)&wt[m * 65536 + h * NN + k0 + kb * 8];
      *(short8*)&wts[(m * 64 + h) * 40 + kb * 8] = val;
    }
    __syncthreads();
    f32x8 af = *(const f32x8*)(xptr + k0);   // A: row=lane&15, k=8g+j (f32)
    short8 a;
#pragma unroll
    for (int e = 0; e < 8; ++e) a[e] = (short)f2bf(af[e]);
#pragma unroll
    for (int m = 0; m < 3; ++m) {
#pragma unroll
      for (int nf = 0; nf < 4; ++nf) {
        short8 bfr = *(const short8*)&wts[(m * 64 + nf * 16 + r) * 40 + 8 * g];
        acc[m][nf] = __builtin_amdgcn_mfma_f32_16x16x32_bf16(a, bfr, acc[m][nf], 0, 0, 0);
      }
    }
    __syncthreads();
  }
  // D layout: col = lane&15 (r), row = 4*g + rr
#pragma unroll
  for (int m = 0; m < 3; ++m) {
    u16* dst = (m == 0) ? qs : (m == 1) ? ks : vs;
    const float sc = (m == 0) ? 0.03125f : 1.0f;
#pragma unroll
    for (int nf = 0; nf < 4; ++nf) {
#pragma unroll
      for (int rr = 0; rr < 4; ++rr) {
        dst[(row0 + 4 * g + rr) * HH + nf * 16 + r] = f2bf(acc[m][nf][rr] * sc);
      }
    }
  }
}

// ---------------------------------------------------------------------------
// Kernel 2: causal flash attention. Block = (q-tile of 64 rows, batch),
// 4 waves x 16 q-rows each. kv-tiles of 64. V staged transposed in LDS,
// P via per-wave LDS round-trip (D-layout -> A-frag layout). Output f32.
// ---------------------------------------------------------------------------
__global__ __launch_bounds__(256) void attn(const u16* __restrict__ qs,
                                            const u16* __restrict__ ks,
                                            const u16* __restrict__ vs,
                                            float* __restrict__ out) {
  __shared__ u16 VT[64 * 72];       // V^T[h][kv], padded stride 72
  __shared__ u16 P[4][16 * 72];     // per-wave P[qrow][kv], padded stride 72
  const int tid = threadIdx.x;
  const int lane = tid & 63;
  const int wv = tid >> 6;
  const int r = lane & 15;
  const int g = lane >> 4;
  const int qt = blockIdx.x;
  const int b = blockIdx.y;
  const int q0 = qt * 64;
  const int rowbase = b * LL + q0 + wv * 16;

  // Q fragments (scale 1/32 already folded in at projection time)
  const short8 qf0 = *(const short8*)&qs[(rowbase + r) * HH + 8 * g];
  const short8 qf1 = *(const short8*)&qs[(rowbase + r) * HH + 32 + 8 * g];

  float mrun[4], lrun[4];
  f32x4 o[4] = {};
#pragma unroll
  for (int rr = 0; rr < 4; ++rr) { mrun[rr] = -1e30f; lrun[rr] = 0.0f; }

  for (int t = 0; t <= qt; ++t) {
    const int kv0 = t * 64;
    __syncthreads();   // prior iteration's VT reads complete
    // stage V^T: 64 kv-rows x 64 h
#pragma unroll
    for (int s = 0; s < 2; ++s) {
      int idx = tid + (s << 8);
      int kvrow = idx >> 3;
      int hb = (idx & 7) * 8;
      short8 vvec = *(const short8*)&vs[(b * LL + kv0 + kvrow) * HH + hb];
#pragma unroll
      for (int e = 0; e < 8; ++e)
        VT[(hb + e) * 72 + kvrow] = (u16)vvec[e];
    }
    __syncthreads();

    // S = Q @ K^T  (B-frag: n = kv row, k = dim, contiguous in K row-major)
    f32x4 s4[4];
#pragma unroll
    for (int nf = 0; nf < 4; ++nf) {
      const u16* kp = &ks[(b * LL + kv0 + nf * 16 + r) * HH + 8 * g];
      short8 b0 = *(const short8*)kp;
      short8 b1 = *(const short8*)(kp + 32);
      f32x4 z = {};
      z = __builtin_amdgcn_mfma_f32_16x16x32_bf16(qf0, b0, z, 0, 0, 0);
      z = __builtin_amdgcn_mfma_f32_16x16x32_bf16(qf1, b1, z, 0, 0, 0);
      s4[nf] = z;
    }
    if (t == qt) {   // diagonal tile: causal mask (tile bases equal)
#pragma unroll
      for (int nf = 0; nf < 4; ++nf) {
#pragma unroll
        for (int rr = 0; rr < 4; ++rr) {
          int col = nf * 16 + r;
          int row = wv * 16 + 4 * g + rr;
          if (col > row) s4[nf][rr] = -1e30f;
        }
      }
    }
    // online softmax: each lane owns rows 4g+rr, cols r(+16nf)
    float pm[4];
#pragma unroll
    for (int rr = 0; rr < 4; ++rr)
      pm[rr] = fmaxf(fmaxf(s4[0][rr], s4[1][rr]), fmaxf(s4[2][rr], s4[3][rr]));
#pragma unroll
    for (int xm = 1; xm <= 8; xm <<= 1) {
#pragma unroll
      for (int rr = 0; rr < 4; ++rr)
        pm[rr] = fmaxf(pm[rr], __shfl_xor(pm[rr], xm));
    }
    float nm[4], al[4], rs[4];
#pragma unroll
    for (int rr = 0; rr < 4; ++rr) {
      nm[rr] = fmaxf(mrun[rr], pm[rr]);
      al[rr] = __expf(mrun[rr] - nm[rr]);
      rs[rr] = 0.0f;
    }
#pragma unroll
    for (int nf = 0; nf < 4; ++nf) {
#pragma unroll
      for (int rr = 0; rr < 4; ++rr) {
        float p = __expf(s4[nf][rr] - nm[rr]);
        s4[nf][rr] = p;
        rs[rr] += p;
      }
    }
#pragma unroll
    for (int xm = 1; xm <= 8; xm <<= 1) {
#pragma unroll
      for (int rr = 0; rr < 4; ++rr)
        rs[rr] += __shfl_xor(rs[rr], xm);
    }
#pragma unroll
    for (int rr = 0; rr < 4; ++rr) {
      lrun[rr] = lrun[rr] * al[rr] + rs[rr];
      mrun[rr] = nm[rr];
    }
#pragma unroll
    for (int hf = 0; hf < 4; ++hf) {
#pragma unroll
      for (int rr = 0; rr < 4; ++rr)
        o[hf][rr] *= al[rr];
    }
    // P: D-layout scatter into per-wave LDS, then read back as A-frags
#pragma unroll
    for (int nf = 0; nf < 4; ++nf) {
#pragma unroll
      for (int rr = 0; rr < 4; ++rr)
        P[wv][(4 * g + rr) * 72 + nf * 16 + r] = f2bf(s4[nf][rr]);
    }
    __syncthreads();
    short8 pa0 = *(const short8*)&P[wv][r * 72 + 8 * g];
    short8 pa1 = *(const short8*)&P[wv][r * 72 + 32 + 8 * g];
#pragma unroll
    for (int hf = 0; hf < 4; ++hf) {
      short8 v0 = *(const short8*)&VT[(hf * 16 + r) * 72 + 8 * g];
      short8 v1 = *(const short8*)&VT[(hf * 16 + r) * 72 + 32 + 8 * g];
      o[hf] = __builtin_amdgcn_mfma_f32_16x16x32_bf16(pa0, v0, o[hf], 0, 0, 0);
      o[hf] = __builtin_amdgcn_mfma_f32_16x16x32_bf16(pa1, v1, o[hf], 0, 0, 0);
    }
  }
  // epilogue: normalize and store (f32 output)
#pragma unroll
  for (int rr = 0; rr < 4; ++rr) {
    float inv = 1.0f / lrun[rr];
#pragma unroll
    for (int hf = 0; hf < 4; ++hf)
      out[(rowbase + 4 * g + rr) * HH + hf * 16 + r] = o[hf][rr] * inv;
  }
}

extern "C" void kernel_launch(void* const* d_in, const int* in_sizes, int n_in,
                              void* d_out, int out_size, void* d_ws, size_t ws_size,
                              hipStream_t stream) {
  const float* x  = (const float*)d_in[0];
  const float* Wk = (const float*)d_in[1];
  const float* Wq = (const float*)d_in[2];
  const float* Wv = (const float*)d_in[3];

  u16* qs = (u16*)d_ws;            // [16384][64] bf16
  u16* ks = qs + BL * HH;
  u16* vs = ks + BL * HH;
  u16* wt = vs + BL * HH;          // [3][64][1024] bf16

  wt_pack<<<768, 256, 0, stream>>>(Wq, Wk, Wv, wt);
  qkv_proj<<<BL / 64, 256, 0, stream>>>(x, wt, qs, ks, vs);
  attn<<<dim3(LL / 64, BQ), 256, 0, stream>>>(qs, ks, vs, (float*)d_out);
}